// Round 9
// baseline (754.228 us; speedup 1.0000x reference)
//
#include <hip/hip_runtime.h>
#include <cstdint>
#include <cstddef>

#define N_    16
#define DIM_  2048
#define RF_   256
#define PN_   64
#define TOPK_ 10
#define HW_   128
#define KFULL (DIM_*HW_)   /* 262144 */
#define KMV   (TOPK_*RF_)  /* 2560 */

#define AS1 __attribute__((address_space(1)))
#define AS3 __attribute__((address_space(3)))

typedef __attribute__((ext_vector_type(8))) short bf16x8;
typedef __attribute__((ext_vector_type(4))) float f32x4;
typedef __attribute__((ext_vector_type(8))) unsigned short u16x8;

__device__ __forceinline__ unsigned short f2bf(float f) {
  unsigned u = __builtin_bit_cast(unsigned, f);
  unsigned r = (u + 0x7FFFu + ((u >> 16) & 1u)) >> 16;
  return (unsigned short)r;
}

// ---------------------------------------------------------------------------
// FRONT kernel (r9): r8 fused three kernels but still read proto TWICE
// (67MB dist + 67MB transpose) and the 512 dist blocks were LDS-pipeline
// heavyweights pacing the dispatch (78us @ 2.6TB/s). Now the transpose role
// computes the dist dot-product itself: each block (p,c0) keeps its proto
// chunk in registers (pv[4]) and dots it against the matching x-chunk
// (262KB, shared by the 64 same-c0 blocks -> L2/L3-resident; x total 16.8MB
// << L3). The dist role is DELETED: no proto re-read, no 2MB part buffer.
// Partials: part2[cb=64][p=64][n=16] (-2*dot), plain stores, select sums.
// Roles: [0,4096) transpose+dot, [4096,4960) cvt. LDS union 33.3KB ->
// 4 blocks/CU.
// ---------------------------------------------------------------------------
__global__ __launch_bounds__(256, 4)
void front_kernel(const float* __restrict__ x, const float* __restrict__ proto,
                  unsigned short* __restrict__ protoT, float* __restrict__ pnorm_part,
                  float* __restrict__ part2,
                  const float* __restrict__ s0, const float* __restrict__ s1,
                  const float* __restrict__ s2, const float* __restrict__ s3,
                  unsigned short* __restrict__ d0, unsigned short* __restrict__ d1,
                  unsigned short* __restrict__ d2, unsigned short* __restrict__ d3,
                  float* __restrict__ dsum) {
  __shared__ alignas(16) unsigned char ldsbuf[33280];
  const int t = threadIdx.x;
  const int bid = blockIdx.x;
  {
    int g = bid * 256 + t;
    if (g < 1152) dsum[g] = 0.f;   // dsum (unused) + flags (64), contiguous
  }

  if (bid < 4096) {
    // ---------------- transpose + dist-dot role ----------------
    float (*tile)[129] = (float (*)[129])ldsbuf;           // 16512 B
    float* ssq = (float*)(ldsbuf + 16512);                 // 16 B
    float (*dred)[16] = (float (*)[16])(ldsbuf + 16528);   // 256 B
    const int p  = bid & 63;
    const int cb = bid >> 6;       // 0..63, c0 = cb*32
    const int c0 = cb * 32;
    const float* sp = proto + ((size_t)p * DIM_ + c0) * HW_;
    float sq = 0.f;
    float4 pv[4];
#pragma unroll
    for (int i = 0; i < 4; ++i) {
      int g = i * 256 + t;
      int ci = g >> 5, s4 = g & 31;
      float4 v = *(const float4*)(sp + (size_t)ci * HW_ + s4 * 4);
      pv[i] = v;
      sq += v.x * v.x + v.y * v.y + v.z * v.z + v.w * v.w;
      int sb = s4 * 4;
      tile[ci][sb] = v.x; tile[ci][sb + 1] = v.y; tile[ci][sb + 2] = v.z; tile[ci][sb + 3] = v.w;
    }

    // x-dot: accn[n] = sum over this thread's 16 chunk elements of x[n].*p
    float accn[16];
#pragma unroll
    for (int n = 0; n < 16; ++n) accn[n] = 0.f;
#pragma unroll
    for (int n = 0; n < 16; ++n) {
      const float* xb = x + (size_t)n * KFULL + (size_t)c0 * HW_;
#pragma unroll
      for (int i = 0; i < 4; ++i) {
        int g = i * 256 + t;
        int ci = g >> 5, s4 = g & 31;
        float4 xv = *(const float4*)(xb + (size_t)ci * HW_ + s4 * 4);
        accn[n] += xv.x * pv[i].x + xv.y * pv[i].y + xv.z * pv[i].z + xv.w * pv[i].w;
      }
    }

#pragma unroll
    for (int m = 1; m < 64; m <<= 1) sq += __shfl_xor(sq, m, 64);
    if ((t & 63) == 0) ssq[t >> 6] = sq;
    __syncthreads();
    if (t == 0) pnorm_part[cb * PN_ + p] = ssq[0] + ssq[1] + ssq[2] + ssq[3];

    // transpose-write protoT (k-quad-major), from LDS tile
    unsigned short* dp = protoT + (size_t)p * HW_ * DIM_ + (size_t)(c0 >> 3) * 1024;
#pragma unroll
    for (int i = 0; i < 2; ++i) {
      int cidx = i * 256 + t;
      int kg = cidx >> 7, s = cidx & 127;
      u16x8 pk;
#pragma unroll
      for (int u = 0; u < 8; ++u) pk[u] = f2bf(tile[kg * 8 + u][s]);
      *(u16x8*)(dp + (size_t)kg * 1024 + (size_t)s * 8) = pk;
    }

    // block-reduce accn (64-lane tree + cross-wave LDS), one plain store
#pragma unroll
    for (int n = 0; n < 16; ++n) {
      float v = accn[n];
#pragma unroll
      for (int m = 1; m < 64; m <<= 1) v += __shfl_xor(v, m, 64);
      if ((t & 63) == 0) dred[t >> 6][n] = v;
    }
    __syncthreads();
    if (t < 16) {
      float s_ = dred[0][t] + dred[1][t] + dred[2][t] + dred[3][t];
      part2[((size_t)cb * 64 + p) * 16 + t] = -2.f * s_;
    }

  } else {
    // ---------------- cvt role (weights -> k-quad-major bf16) ----------------
    u16x8 (*ctile)[65] = (u16x8 (*)[65])ldsbuf;           // 33280 B
    int local = bid - 4096;
    const float* s; unsigned short* d; int O, CG, tb;
    if (local < 32)       { s = s0; d = d0; O = RF_;  CG = DIM_ / 8; tb = local; }
    else if (local < 352) { s = s1; d = d1; O = DIM_; CG = KMV  / 8; tb = local - 32; }
    else if (local < 608) { s = s2; d = d2; O = DIM_; CG = DIM_ / 8; tb = local - 352; }
    else                  { s = s3; d = d3; O = DIM_; CG = DIM_ / 8; tb = local - 608; }
    const int nCgT = CG / 32;
    const int o0  = (tb / nCgT) * 64;
    const int cg0 = (tb % nCgT) * 32;
    const size_t C = (size_t)CG * 8;

#pragma unroll
    for (int i = 0; i < 8; ++i) {
      int idx = i * 256 + t, ol = idx >> 5, cg = idx & 31;
      const float* sp = s + (size_t)(o0 + ol) * C + (size_t)(cg0 + cg) * 8;
      float4 a = *(const float4*)sp;
      float4 b = *(const float4*)(sp + 4);
      u16x8 pk;
      pk[0] = f2bf(a.x); pk[1] = f2bf(a.y); pk[2] = f2bf(a.z); pk[3] = f2bf(a.w);
      pk[4] = f2bf(b.x); pk[5] = f2bf(b.y); pk[6] = f2bf(b.z); pk[7] = f2bf(b.w);
      ctile[cg][ol] = pk;
    }
    __syncthreads();
#pragma unroll
    for (int i = 0; i < 8; ++i) {
      int idx = i * 256 + t, cg = idx >> 6, ol = idx & 63;
      *(u16x8*)(d + (size_t)(cg0 + cg) * ((size_t)O * 8) + (size_t)(o0 + ol) * 8) =
          ctile[cg][ol];
    }
  }
}

// ---------------------------------------------------------------------------
// select: 512 threads; lane c = prototype p, chunk-group ch sums 8 of the 64
// cb-partials from part2[cb][p][n] (262KB, L2-resident), LDS combine, first
// 64 lanes add ||p||^2 and rank (stable argsort order). flags[] pre-zeroed
// by front; benign same-value race across blocks.
// ---------------------------------------------------------------------------
__global__ __launch_bounds__(512)
void select_kernel(const float* __restrict__ part2, const float* __restrict__ pnorm_part,
                   int* __restrict__ idx, int* __restrict__ flags) {
  __shared__ float red[8][64];
  __shared__ float sh[64];
  const int n = blockIdx.x, t = threadIdx.x;
  const int c = t & 63, ch = t >> 6;
  float a = 0.f;
#pragma unroll
  for (int j = 0; j < 8; ++j) {
    int cb = ch + j * 8;
    a += part2[((size_t)cb * 64 + c) * 16 + n];
  }
  red[ch][c] = a;
  __syncthreads();
  if (t < 64) {
    float pn = 0.f;
#pragma unroll 8
    for (int cb = 0; cb < DIM_ / 32; ++cb) pn += pnorm_part[cb * PN_ + t];
    float dv = pn;
#pragma unroll
    for (int i = 0; i < 8; ++i) dv += red[i][t];
    sh[t] = dv;
  }
  __syncthreads();
  if (t < 64) {
    float dval = sh[t];
    int rank = 0;
#pragma unroll
    for (int j = 0; j < 64; ++j) {
      float o = sh[j];
      rank += (o < dval || (o == dval && j < t)) ? 1 : 0;
    }
    if (rank < TOPK_) { idx[n * TOPK_ + rank] = t; flags[t] = 1; }
  }
}

// ---------------------------------------------------------------------------
// bf16 MFMA GEMM, tile 64Mx128Nx64K, 512 threads = 8 waves (unchanged from
// r8). Wave w owns a 16x64 tile (m-quarter = w>>1, n-half = w&1), acc[4],
// 3 staging loads/wave, depth-2 prefetch -> counted vmcnt(3); 3-buffer
// pipeline, 16 waves/CU. All staged tensors k-quad-major (W'[kq][O][8],
// X'[batch][kq][s][8]): every global_load_lds reads ONE contiguous 1KB run.
// LDS: A cell(qk,m)=16B @ qk*1024B + m*16B; B cell(qk,n)=qk*2048B + n*16B.
// ---------------------------------------------------------------------------
#define BM 64
#define BKK 64

template <int MODE>
__global__ __launch_bounds__(512, 4)
void mfma_gemm_kernel(const unsigned short* __restrict__ Wb,
                      const unsigned short* __restrict__ Xb,
                      void* __restrict__ OutP,
                      const float* __restrict__ inputs,
                      const int* __restrict__ idxp,
                      const int* __restrict__ flags,
                      int K, int O, int Ldim) {
  __shared__ alignas(16) unsigned short Al[3][8 * BM * 8];    // 3 x 8 KB
  __shared__ alignas(16) unsigned short Bl[3][8 * 128 * 8];   // 3 x 16 KB

  const int t = threadIdx.x;
  const int w = t >> 6;          // wave 0..7
  const int lane = t & 63;
  const int q = lane >> 4;
  const int l15 = lane & 15;
  const int mq = w >> 1;         // m-quarter (16 rows)
  const int h  = w & 1;          // n-half (64 cols)
  const int batch = blockIdx.y;
  const int o0 = blockIdx.x * BM;

  if (MODE == 0 && flags && !flags[batch]) return;

  int idreg = 0;
  if (MODE == 1 && lane < TOPK_) idreg = idxp[batch * TOPK_ + lane];

  f32x4 acc[4] = {};

  auto issue = [&](int k0, int buf) {
    // A: wave w stages k-quad w (one contiguous 1KB load of W'[kq][O][8])
    {
      const unsigned short* ga =
          Wb + (size_t)((k0 >> 3) + w) * (O * 8) + (size_t)(o0 + lane) * 8;
      __builtin_amdgcn_global_load_lds((const AS1 void*)ga,
                                       (AS3 void*)(&Al[buf][w * 512]), 16, 0, 0);
    }
    const unsigned short* base;
    if (MODE == 1) {
      int id = __shfl(idreg, k0 >> 8, 64);
      base = Xb + (size_t)id * (HW_ * RF_) + (size_t)((k0 & 255) >> 3) * 1024;
    } else {
      base = Xb + (size_t)batch * HW_ * K + (size_t)(k0 >> 3) * 1024;
    }
    // B: wave w stages 2 of 16 (qk, half) 1KB regions of X'[kq][s][8].
#pragma unroll
    for (int i = 0; i < 2; ++i) {
      int v = w * 2 + i;
      int qk = v >> 1, hh = v & 1;
      const unsigned short* gb = base + (size_t)qk * 1024 + (size_t)(hh * 64 + lane) * 8;
      __builtin_amdgcn_global_load_lds((const AS1 void*)gb,
                                       (AS3 void*)(&Bl[buf][qk * 1024 + hh * 512]), 16, 0, 0);
    }
  };

  const int nIter = K / BKK;   // 32 (MODE 0/2/3) or 40 (MODE 1)

  issue(0, 0);
  issue(BKK, 1);               // 6 loads/wave outstanding

  for (int it = 0; it < nIter; ++it) {
    const int buf = it % 3;
    if (it + 1 < nIter) {
      asm volatile("s_waitcnt vmcnt(3)" ::: "memory");
    } else {
      asm volatile("s_waitcnt vmcnt(0)" ::: "memory");
    }
    __builtin_amdgcn_s_barrier();
#pragma unroll
    for (int s = 0; s < 2; ++s) {
      bf16x8 af, bfr[4];
      af = *(const bf16x8*)(&Al[buf][(s * 4 + q) * 512 + (mq * 16 + l15) * 8]);
#pragma unroll
      for (int nt = 0; nt < 4; ++nt)
        bfr[nt] = *(const bf16x8*)(&Bl[buf][(s * 4 + q) * 1024 + (h * 64 + nt * 16 + l15) * 8]);
#pragma unroll
      for (int nt = 0; nt < 4; ++nt)
        acc[nt] = __builtin_amdgcn_mfma_f32_16x16x32_bf16(af, bfr[nt], acc[nt], 0, 0, 0);
    }
    if (it + 2 < nIter) issue((it + 2) * BKK, (it + 2) % 3);
  }

  // ---------------- epilogue ----------------
  const float CAL = 1.0f - 1.0f / 262144.0f;

  float* nsumS = (float*)&Al[0][0];         // [8][16]
  float* nsqS  = (float*)&Al[0][0] + 128;   // [8][16]

  if (MODE == 2) {
#pragma unroll
    for (int reg = 0; reg < 4; ++reg) {
      float s_ = 0.f, q_ = 0.f;
#pragma unroll
      for (int nt = 0; nt < 4; ++nt) {
        float v = acc[nt][reg];
        s_ += v; q_ += v * v;
      }
#pragma unroll
      for (int m = 1; m < 16; m <<= 1) {
        s_ += __shfl_xor(s_, m, 64);
        q_ += __shfl_xor(q_, m, 64);
      }
      if (l15 == 0) {
        nsumS[w * 16 + q * 4 + reg] = s_;
        nsqS [w * 16 + q * 4 + reg] = q_;
      }
    }
    __syncthreads();
  }

  if (MODE == 3) {
    float* ofb = (float*)OutP + (size_t)batch * DIM_ * HW_;
    const float* inb = inputs + (size_t)batch * DIM_ * HW_;
#pragma unroll
    for (int nt = 0; nt < 4; ++nt) {
      int o = o0 + mq * 16 + q * 4;
      int s = h * 64 + nt * 16 + l15;
      f32x4 v = acc[nt];
#pragma unroll
      for (int g = 0; g < 4; ++g) {
        float in = inb[(size_t)(o + g) * HW_ + s];
        float sg = 1.f / (1.f + expf(-v[g]));
        ofb[(size_t)(o + g) * HW_ + s] = in * (1.f + sg);
      }
    }
  } else {
    unsigned short* ob = (unsigned short*)OutP + (size_t)batch * HW_ * Ldim;
    const float* inb = (MODE == 1) ? inputs + (size_t)batch * DIM_ * HW_ : nullptr;
    float mean[4], rs[4];
    if (MODE == 2) {
#pragma unroll
      for (int reg = 0; reg < 4; ++reg) {
        int ol = q * 4 + reg;
        float ts = nsumS[(mq * 2 + 0) * 16 + ol] + nsumS[(mq * 2 + 1) * 16 + ol];
        float tq = nsqS [(mq * 2 + 0) * 16 + ol] + nsqS [(mq * 2 + 1) * 16 + ol];
        float mn = ts * (1.f / 128.f);
        float vr = tq * (1.f / 128.f) - mn * mn;
        mean[reg] = mn; rs[reg] = rsqrtf(vr + 1e-5f);
      }
    }
#pragma unroll
    for (int nt = 0; nt < 4; ++nt) {
      int o = o0 + mq * 16 + q * 4;
      int s = h * 64 + nt * 16 + l15;
      f32x4 v = acc[nt];
      float r[4];
      if (MODE == 0) {
#pragma unroll
        for (int g = 0; g < 4; ++g) r[g] = v[g];
      } else if (MODE == 1) {
        const float* ip = inb + (size_t)o * HW_ + s;
#pragma unroll
        for (int g = 0; g < 4; ++g)
          r[g] = fmaxf(0.f, 0.5f * ip[(size_t)g * HW_] + CAL * v[g]);
      } else {
#pragma unroll
        for (int g = 0; g < 4; ++g) r[g] = (v[g] - mean[g]) * rs[g];
      }
      ushort4 pk;
      pk.x = f2bf(r[0]); pk.y = f2bf(r[1]); pk.z = f2bf(r[2]); pk.w = f2bf(r[3]);
      *(ushort4*)(ob + (size_t)(o >> 3) * 1024 + (size_t)s * 8 + (o & 7)) = pk;
    }
  }
}

// ---------------------------------------------------------------------------
extern "C" void kernel_launch(void* const* d_in, const int* in_sizes, int n_in,
                              void* d_out, int out_size, void* d_ws, size_t ws_size,
                              hipStream_t stream) {
  const float* inputs = (const float*)d_in[0];
  const float* proto  = (const float*)d_in[1];
  const float* w_rf   = (const float*)d_in[2];
  const float* w_rfmv = (const float*)d_in[3];
  const float* w_rms  = (const float*)d_in[4];
  const float* w_fuse = (const float*)d_in[5];
  float* out = (float*)d_out;

  uint8_t* ws = (uint8_t*)d_ws;
  size_t off = 0;
  auto alloc = [&](size_t bytes) { uint8_t* p = ws + off; off += (bytes + 255) & ~(size_t)255; return p; };

  float* dsum  = (float*)alloc(1088 * 4);       // 4352 B (256-aligned size)
  int*   flags = (int*)alloc(PN_ * 4);          // contiguous after dsum -> zeroed together
  int*   idx   = (int*)alloc(N_ * TOPK_ * 4);
  float* pnorm = (float*)alloc((size_t)(DIM_ / 32) * PN_ * 4);   // 64x64 partials
  float* part2 = (float*)alloc((size_t)64 * 64 * 16 * 4);        // 262KB dot partials
  unsigned short* wrf_b   = (unsigned short*)alloc((size_t)RF_ * DIM_ * 2);
  unsigned short* wrfmv_b = (unsigned short*)alloc((size_t)DIM_ * KMV * 2);
  unsigned short* wrms_b  = (unsigned short*)alloc((size_t)DIM_ * DIM_ * 2);
  unsigned short* wfuse_b = (unsigned short*)alloc((size_t)DIM_ * DIM_ * 2);
  unsigned short* xpT     = (unsigned short*)alloc((size_t)PN_ * HW_ * RF_ * 2);
  unsigned short* protoT  = (unsigned short*)alloc((size_t)PN_ * HW_ * DIM_ * 2);
  unsigned short* mvlT = protoT;                 // aliases (protoT dead after G1)
  unsigned short* mvaT = protoT + (size_t)N_ * HW_ * DIM_;

  front_kernel<<<4960, 256, 0, stream>>>(inputs, proto, protoT, pnorm, part2,
                                         w_rf, w_rfmv, w_rms, w_fuse,
                                         wrf_b, wrfmv_b, wrms_b, wfuse_b, dsum);
  select_kernel<<<N_, 512, 0, stream>>>(part2, pnorm, idx, flags);

  mfma_gemm_kernel<0><<<dim3(RF_ / BM, PN_), 512, 0, stream>>>(
      wrf_b, protoT, xpT, nullptr, nullptr, flags, DIM_, RF_, RF_);
  mfma_gemm_kernel<1><<<dim3(DIM_ / BM, N_), 512, 0, stream>>>(
      wrfmv_b, xpT, mvlT, inputs, idx, nullptr, KMV, DIM_, DIM_);
  mfma_gemm_kernel<2><<<dim3(DIM_ / BM, N_), 512, 0, stream>>>(
      wrms_b, mvlT, mvaT, nullptr, nullptr, nullptr, DIM_, DIM_, DIM_);
  mfma_gemm_kernel<3><<<dim3(DIM_ / BM, N_), 512, 0, stream>>>(
      wfuse_b, mvaT, out, inputs, nullptr, nullptr, DIM_, DIM_, DIM_);
}